// Round 2
// 267.685 us; speedup vs baseline: 1.0849x; 1.0849x over previous
//
#include <hip/hip_runtime.h>

// Problem constants (from reference): B=64, J=32, M=160, N=160
#define BB 64
#define JJ 32
#define MM 160
#define NN 160
#define MNV (MM * NN)          // 25600 floats per (b,j) map
#define MNV4 (MNV / 4)         // 6400 float4

// Native vector type for __builtin_nontemporal_load (HIP_vector_type is a
// struct and the builtin rejects it; ext_vector_type lowers identically to
// global_load_dwordx4 with the 'nt' cache policy).
typedef float nfloat4 __attribute__((ext_vector_type(4)));

// Phase 1: one block per (b,j). Argmax over the 160x160 map + per-object
// loss, written to ws[bj]. No atomics, no pre-zero needed.
__global__ __launch_bounds__(256) void label_loss_kernel(
    const float* __restrict__ pred,    // (B, 9, J, 1)
    const float* __restrict__ gt,      // (B, J, 11)
    const float* __restrict__ heatmap, // (B, J, M, N)
    float* __restrict__ ws)            // (B*J,) per-object losses
{
    const int bj = blockIdx.x;         // 0 .. B*J-1
    const int b  = bj / JJ;
    const int j  = bj % JJ;
    const int tid = threadIdx.x;

    // ---- prefetch gt/pred for this (b,j) into LDS at kernel entry ----
    // These loads issue before the heatmap scan; their latency hides under
    // the 25-iteration streaming loop, removing the dependent-load chain
    // from the tid==0 epilogue (was on every block's retirement path).
    __shared__ float sg[11];   // gt[bj][0..10]
    __shared__ float sp[9];    // pred[b][0..8][j][0]
    if (tid < 11) {
        sg[tid] = gt[(size_t)bj * 11 + tid];
    } else if (tid < 20) {
        const int c = tid - 11;
        sp[c] = pred[((size_t)b * 9 + c) * JJ + j];
    }

    const nfloat4* __restrict__ hm4 =
        (const nfloat4*)(heatmap + (size_t)bj * MNV);

    // ---- per-thread argmax: 4 INDEPENDENT chains (one per float4 lane) ----
    // Ascending traversal + strict '>' keeps the first occurrence per chain.
    // Nontemporal: heatmap is stream-once; don't let it thrash L2.
    float bv0 = -INFINITY, bv1 = -INFINITY, bv2 = -INFINITY, bv3 = -INFINITY;
    int   bi0 = 0, bi1 = 0, bi2 = 0, bi3 = 0;
    #pragma unroll 5
    for (int i = tid; i < MNV4; i += 256) {
        nfloat4 v = __builtin_nontemporal_load(hm4 + i);
        int base = i << 2;
        if (v.x > bv0) { bv0 = v.x; bi0 = base;     }
        if (v.y > bv1) { bv1 = v.y; bi1 = base + 1; }
        if (v.z > bv2) { bv2 = v.z; bi2 = base + 2; }
        if (v.w > bv3) { bv3 = v.w; bi3 = base + 3; }
    }

    // merge the 4 chains (lowest-index tie-break => first occurrence)
    float best = bv0; int bestIdx = bi0;
    if (bv1 > best || (bv1 == best && bi1 < bestIdx)) { best = bv1; bestIdx = bi1; }
    if (bv2 > best || (bv2 == best && bi2 < bestIdx)) { best = bv2; bestIdx = bi2; }
    if (bv3 > best || (bv3 == best && bi3 < bestIdx)) { best = bv3; bestIdx = bi3; }

    // ---- wave (64-lane) reduction with lowest-index tie-break ----
    #pragma unroll
    for (int off = 32; off > 0; off >>= 1) {
        float ov = __shfl_down(best,    off, 64);
        int   oi = __shfl_down(bestIdx, off, 64);
        if (ov > best || (ov == best && oi < bestIdx)) {
            best = ov; bestIdx = oi;
        }
    }

    // ---- cross-wave reduction (4 waves per block) ----
    __shared__ float svals[4];
    __shared__ int   sidxs[4];
    const int wave = tid >> 6;
    if ((tid & 63) == 0) { svals[wave] = best; sidxs[wave] = bestIdx; }
    __syncthreads();   // also publishes sg[]/sp[] prefetch

    if (tid == 0) {
        #pragma unroll
        for (int w = 1; w < 4; ++w) {
            float ov = svals[w];
            int   oi = sidxs[w];
            if (ov > best || (ov == best && oi < bestIdx)) {
                best = ov; bestIdx = oi;
            }
        }

        // x = idx // M ; y = idx % M   (row-major M*N flatten, M==N==160)
        const float x = (float)(bestIdx / MM);
        const float y = (float)(bestIdx % MM);

        const float g9  = sg[9];
        const float g10 = sg[10];
        const bool valid = (g9 > 0.0f) && (g10 > 0.0f) &&
                           (g9 < (float)MM) && (g10 < (float)NN);

        float loss = 0.0f;
        if (valid) {
            float cls = 0.0f;
            #pragma unroll
            for (int k = 0; k < 7; ++k) {
                float d = sp[k] - sg[k];
                cls += d * d;
            }
            const float px = sp[7];
            const float py = sp[8];
            const float dx = g9  + sg[7] - x - px;
            const float dy = g10 + sg[8] - y - py;
            loss = cls + dx * dx + dy * dy;
        }
        ws[bj] = loss;
    }
}

// Phase 2: one wave; thread b sums its 32 contiguous per-object losses.
// Writes ALL 64 outputs -> no zero-init of d_out needed.
__global__ __launch_bounds__(64) void reduce_kernel(
    const float* __restrict__ ws, float* __restrict__ out)
{
    const int b = threadIdx.x;   // 0..63
    const float4* __restrict__ w4 = (const float4*)(ws + b * JJ);
    float s = 0.0f;
    #pragma unroll
    for (int k = 0; k < JJ / 4; ++k) {
        float4 v = w4[k];
        s += v.x + v.y + v.z + v.w;
    }
    out[b] = s;
}

extern "C" void kernel_launch(void* const* d_in, const int* in_sizes, int n_in,
                              void* d_out, int out_size, void* d_ws, size_t ws_size,
                              hipStream_t stream) {
    const float* pred    = (const float*)d_in[0];
    const float* gt      = (const float*)d_in[1];
    const float* heatmap = (const float*)d_in[2];
    float* ws  = (float*)d_ws;
    float* out = (float*)d_out;

    label_loss_kernel<<<BB * JJ, 256, 0, stream>>>(pred, gt, heatmap, ws);
    reduce_kernel<<<1, BB, 0, stream>>>(ws, out);
}